// Round 5
// baseline (305.743 us; speedup 1.0000x reference)
//
#include <hip/hip_runtime.h>
#include <hip/hip_bf16.h>

#define NV 512
#define NF 64

typedef __attribute__((ext_vector_type(8))) short bf16x8;
typedef __attribute__((ext_vector_type(4))) float f32x4;

union BF8 { bf16x8 v; unsigned u[4]; };

__device__ __forceinline__ unsigned short f2bf(float x) {
    unsigned u = __float_as_uint(x);
    unsigned r = (u + 0x7fffu + ((u >> 16) & 1u)) >> 16;
    return (unsigned short)r;
}

// AwT byte address: row f (1KB each), j-byte jb; XOR-swz mixes f's bits 0-2 AND 3-5
// so both staging writes (f stride 4) and GEMM reads (f stride 1) spread over 8 slots.
__device__ __forceinline__ unsigned awt_addr(int f, int jbyte) {
    return (unsigned)((f * 1024 + jbyte) ^ (((f ^ (f >> 3)) & 7) << 4));
}

__global__ void k_zero(unsigned int* mask) {
    mask[blockIdx.x * 256 + threadIdx.x] = 0u;
}

__global__ void k_edges(const int* __restrict__ ei, int E, unsigned int* __restrict__ mask) {
    int e = blockIdx.x * 256 + threadIdx.x;
    if (e < E) {
        int s = ei[e];       // src  (edge_index[0])
        int d = ei[E + e];   // dst  (edge_index[1])
        atomicOr(&mask[d * 16 + (s >> 5)], 1u << (s & 31));
    }
}

// one wave per v: S[v,:] = sum_{j in N(v)} alpha[v*V+j,:]  (dedup'd via bitmask)
__global__ void k_S(const unsigned int* __restrict__ mask, const float* __restrict__ alpha,
                    float* __restrict__ S) {
    int v = blockIdx.x;
    int f = threadIdx.x;   // 64 threads
    float acc = 0.f;
    for (int wd = 0; wd < 16; ++wd) {
        unsigned int bits = mask[v * 16 + wd];
        while (bits) {
            int b = __ffs(bits) - 1;
            bits &= bits - 1;
            int j = wd * 32 + b;
            acc += alpha[((size_t)v * NV + j) * NF + f];
        }
    }
    S[v * NF + f] = acc;
}

// LDS (81920 B total -> 2 blocks/CU):
//   [0, 65536)       AwT bf16 [64 f][512 j], swizzled (awt_addr)
//   [65536, 81920)   scr bf16 per-wave [16 rows][64], row-XOR swz, 2KB/wave
#define SCR_OFF 65536

__global__ __launch_bounds__(512, 4) void k_main(
    const float* __restrict__ alpha, const float* __restrict__ w1, const float* __restrict__ b1,
    const float* __restrict__ w2, const float* __restrict__ b2, const float* __restrict__ eps_p,
    const unsigned int* __restrict__ mask, const float* __restrict__ S,
    float* __restrict__ out)
{
    extern __shared__ char smem[];

    const int w    = blockIdx.x;
    const int t    = threadIdx.x;
    const int lane = t & 63;
    const int wid  = t >> 6;
    const int nlo  = lane & 15;
    const int g    = lane >> 4;
    const int kbase = g * 8;
    const float ceps = 1.0f + eps_p[0];

    // ---- stage AwT (bf16, transposed, swizzled): AwT[f][j] = alpha[w*512+j][f] ----
    {
        const float* src = alpha + (size_t)w * (NV * NF);
#pragma unroll
        for (int i = 0; i < 2; ++i) {
            int task = i * 512 + t;          // 1024 tasks: 64 j-blocks x 16 f-quads
            int jb = task >> 4;              // j block of 8 rows
            int fq = task & 15;              // f quad (4 cols)
            f32x4 rows[8];
#pragma unroll
            for (int r = 0; r < 8; ++r)
                rows[r] = *(const f32x4*)(src + (size_t)(jb * 8 + r) * NF + fq * 4);
#pragma unroll
            for (int c = 0; c < 4; ++c) {
                int f = fq * 4 + c;
                BF8 p;
#pragma unroll
                for (int h = 0; h < 4; ++h) {
                    unsigned lo = f2bf(rows[2 * h][c]);
                    unsigned hi = f2bf(rows[2 * h + 1][c]);
                    p.u[h] = lo | (hi << 16);
                }
                *(bf16x8*)(smem + awt_addr(f, jb * 16)) = p.v;
            }
        }
    }
    __syncthreads();

    char* myscr = smem + SCR_OFF + wid * 2048;   // [16][64] bf16, row 128B, XOR swz

    // ---- two halves of 32 v-rows each; keeps live acc at 2x4 (32 regs) ----
#pragma unroll 1
    for (int half = 0; half < 2; ++half) {
        const int hbase = wid * 64 + half * 32;

        // mask words for this half's 2 m-tiles (8 regs; row = hbase+mi*16+nlo)
        unsigned qm[2][4];
#pragma unroll
        for (int mi = 0; mi < 2; ++mi) {
            const uint4 q = *(const uint4*)(mask + (size_t)(hbase + mi * 16 + nlo) * 16 + g * 4);
            qm[mi][0] = q.x; qm[mi][1] = q.y; qm[mi][2] = q.z; qm[mi][3] = q.w;
        }

        f32x4 acc[2][4];
#pragma unroll
        for (int mi = 0; mi < 2; ++mi)
#pragma unroll
            for (int nt = 0; nt < 4; ++nt)
                acc[mi][nt] = (f32x4){0.f, 0.f, 0.f, 0.f};

        // adjacency GEMM: pre[v][f] = sum_j adj[v,j]*Aw[j][f]
#pragma unroll
        for (int kq = 0; kq < 4; ++kq)
#pragma unroll
            for (int kr = 0; kr < 4; ++kr) {
                const int kk = kq * 4 + kr;
                bf16x8 bfr[4];
#pragma unroll
                for (int nt = 0; nt < 4; ++nt) {
                    int f = nt * 16 + nlo;
                    bfr[nt] = *(const bf16x8*)(smem + awt_addr(f, kk * 64 + g * 16));
                }
                const int srcl = kq * 16 + nlo;   // holder lane of word kk for my row
#pragma unroll
                for (int mi = 0; mi < 2; ++mi) {
                    unsigned word = (unsigned)__shfl((int)qm[mi][kr], srcl);
                    unsigned byteb = (word >> (g * 8)) & 0xFFu;
                    BF8 a;
#pragma unroll
                    for (int h = 0; h < 4; ++h) {
                        unsigned b0 = (byteb >> (2 * h)) & 1u;
                        unsigned b1 = (byteb >> (2 * h + 1)) & 1u;
                        a.u[h] = (b0 ? 0x3F80u : 0u) | (b1 ? 0x3F800000u : 0u);
                    }
#pragma unroll
                    for (int nt = 0; nt < 4; ++nt)
                        acc[mi][nt] = __builtin_amdgcn_mfma_f32_16x16x32_bf16(a.v, bfr[nt], acc[mi][nt], 0, 0, 0);
                }
            }

        // ---- MLP weight frags (rebuilt per half, after GEMM: never live with acc) ----
        // phi: lane l, frag(ks,nt), elem e <-> k = ks*32 + (l>>4)*8 + e, n = nt*16 + (l&15)
        bf16x8 w1f[2][4], w2f[2][4];
#pragma unroll
        for (int ks = 0; ks < 2; ++ks)
#pragma unroll
            for (int nt = 0; nt < 4; ++nt) {
                bf16x8 a, b;
#pragma unroll
                for (int e = 0; e < 8; ++e) {
                    int k = ks * 32 + kbase + e;
                    a[e] = (short)f2bf(w1[k * NF + nt * 16 + nlo]);
                    b[e] = (short)f2bf(w2[k * NF + nt * 16 + nlo]);
                }
                w1f[ks][nt] = a;
                w2f[ks][nt] = b;
            }
        float b1v[4], b2v[4];
#pragma unroll
        for (int nt = 0; nt < 4; ++nt) {
            b1v[nt] = b1[nt * 16 + nlo];
            b2v[nt] = b2[nt * 16 + nlo];
        }

        // ---- epilogue per m-tile: +S +ceps*rv -> bf16 scr -> MLP (MFMA) -> out ----
#pragma unroll
        for (int mi = 0; mi < 2; ++mi) {
            int v0 = hbase + mi * 16;
#pragma unroll
            for (int nt = 0; nt < 4; ++nt) {
                int f = nt * 16 + nlo;
#pragma unroll
                for (int r = 0; r < 4; ++r) {
                    int v = v0 + g * 4 + r;
                    float pre = acc[mi][nt][r] + S[v * NF + f]
                              + ceps * alpha[((size_t)v * NV + w) * NF + f];
                    int row = g * 4 + r;
                    *(unsigned short*)(myscr + row * 128 + ((2 * f) ^ ((row & 7) << 4))) = f2bf(pre);
                }
            }

            // layer 1  (A-frag: row nlo, k-bytes g*16 + ks*64, row-XOR swz)
            bf16x8 a0 = *(const bf16x8*)(myscr + nlo * 128 + ((g * 16) ^ ((nlo & 7) << 4)));
            bf16x8 a1 = *(const bf16x8*)(myscr + nlo * 128 + ((g * 16 + 64) ^ ((nlo & 7) << 4)));
            f32x4 accm[4];
#pragma unroll
            for (int nt = 0; nt < 4; ++nt) {
                f32x4 z = {0.f, 0.f, 0.f, 0.f};
                z = __builtin_amdgcn_mfma_f32_16x16x32_bf16(a0, w1f[0][nt], z, 0, 0, 0);
                z = __builtin_amdgcn_mfma_f32_16x16x32_bf16(a1, w1f[1][nt], z, 0, 0, 0);
                accm[nt] = z;
            }

            // relu + b1 -> scr (C/D: row=(l>>4)*4+r, col=nt*16+(l&15))
#pragma unroll
            for (int nt = 0; nt < 4; ++nt)
#pragma unroll
                for (int r = 0; r < 4; ++r) {
                    float hv = accm[nt][r] + b1v[nt];
                    hv = hv > 0.f ? hv : 0.f;
                    int row = g * 4 + r;
                    *(unsigned short*)(myscr + row * 128 + ((2 * (nt * 16 + nlo)) ^ ((row & 7) << 4))) = f2bf(hv);
                }

            // layer 2
            bf16x8 h0 = *(const bf16x8*)(myscr + nlo * 128 + ((g * 16) ^ ((nlo & 7) << 4)));
            bf16x8 h1 = *(const bf16x8*)(myscr + nlo * 128 + ((g * 16 + 64) ^ ((nlo & 7) << 4)));
#pragma unroll
            for (int nt = 0; nt < 4; ++nt) {
                f32x4 z = {0.f, 0.f, 0.f, 0.f};
                z = __builtin_amdgcn_mfma_f32_16x16x32_bf16(h0, w2f[0][nt], z, 0, 0, 0);
                z = __builtin_amdgcn_mfma_f32_16x16x32_bf16(h1, w2f[1][nt], z, 0, 0, 0);
#pragma unroll
                for (int r = 0; r < 4; ++r) {
                    int vv = v0 + g * 4 + r;
                    out[((size_t)vv * NV + w) * NF + nt * 16 + nlo] = z[r] + b2v[nt];
                }
            }
        }
    }
}

extern "C" void kernel_launch(void* const* d_in, const int* in_sizes, int n_in,
                              void* d_out, int out_size, void* d_ws, size_t ws_size,
                              hipStream_t stream) {
    const float* alpha = (const float*)d_in[0];
    const int*   ei    = (const int*)d_in[1];
    const float* w1    = (const float*)d_in[2];
    const float* b1    = (const float*)d_in[3];
    const float* w2    = (const float*)d_in[4];
    const float* b2    = (const float*)d_in[5];
    const float* eps   = (const float*)d_in[6];
    float* out = (float*)d_out;
    int E = in_sizes[1] / 2;

    // ws layout (u32/f32 units): mask[8192] | S[512*64]
    unsigned int* mask = (unsigned int*)d_ws;
    float* S = (float*)d_ws + 8192;

    k_zero <<<32, 256, 0, stream>>>(mask);
    k_edges<<<(E + 255) / 256, 256, 0, stream>>>(ei, E, mask);
    k_S    <<<NV, 64, 0, stream>>>(mask, alpha, S);

    const int smem_bytes = 81920;   // 64K AwT + 16K scr -> exactly 2 blocks/CU
    hipFuncSetAttribute(reinterpret_cast<const void*>(k_main),
                        hipFuncAttributeMaxDynamicSharedMemorySize, smem_bytes);
    k_main <<<NV, 512, smem_bytes, stream>>>(alpha, w1, b1, w2, b2, eps, mask, S, out);
}

// Round 6
// 70.886 us; speedup vs baseline: 4.3132x; 4.3132x over previous
//
#include <hip/hip_runtime.h>
#include <hip/hip_bf16.h>

#define NV 512
#define NF 64

typedef __attribute__((ext_vector_type(8))) short bf16x8;
typedef __attribute__((ext_vector_type(4))) float f32x4;

union BF8 { bf16x8 v; unsigned u[4]; };

__device__ __forceinline__ unsigned short f2bf(float x) {
    unsigned u = __float_as_uint(x);
    unsigned r = (u + 0x7fffu + ((u >> 16) & 1u)) >> 16;
    return (unsigned short)r;
}

// AwT byte address: row f (1KB each); XOR-swz mixes f bits 0-2 and 3-5 so both
// staging writes (f stride 4) and GEMM reads (f stride 1) are conflict-free.
__device__ __forceinline__ unsigned awt_addr(int f, int jbyte) {
    return (unsigned)((f * 1024 + jbyte) ^ (((f ^ (f >> 3)) & 7) << 4));
}
// wT (transposed weights) in LDS: matrix m (0=w1,1=w2), row n (128B), kbyte.
__device__ __forceinline__ unsigned wt_addr(int m, int n, int kbyte) {
    return (unsigned)(m * 8192 + ((n * 128 + kbyte) ^ (((n ^ (n >> 3)) & 7) << 4)));
}

__global__ void k_zero(unsigned int* mask) {
    mask[blockIdx.x * 256 + threadIdx.x] = 0u;
}

__global__ void k_edges(const int* __restrict__ ei, int E, unsigned int* __restrict__ mask) {
    int e = blockIdx.x * 256 + threadIdx.x;
    if (e < E) {
        int s = ei[e];       // src  (edge_index[0])
        int d = ei[E + e];   // dst  (edge_index[1])
        atomicOr(&mask[d * 16 + (s >> 5)], 1u << (s & 31));
    }
}

// one wave per v: S[v,:] = sum_{j in N(v)} alpha[v*V+j,:]  (dedup'd via bitmask)
__global__ void k_S(const unsigned int* __restrict__ mask, const float* __restrict__ alpha,
                    float* __restrict__ S) {
    int v = blockIdx.x;
    int f = threadIdx.x;   // 64 threads
    float acc = 0.f;
    for (int wd = 0; wd < 16; ++wd) {
        unsigned int bits = mask[v * 16 + wd];
        while (bits) {
            int b = __ffs(bits) - 1;
            bits &= bits - 1;
            int j = wd * 32 + b;
            acc += alpha[((size_t)v * NV + j) * NF + f];
        }
    }
    S[v * NF + f] = acc;
}

// LDS (81920 B -> 2 blocks/CU):
//   [0, 65536)      AwT bf16 [64 f][512 j] swizzled; after GEMM the first 16KB
//                   is reused for w1T/w2T (staged post-barrier, acc safe in AGPRs)
//   [65536, 81920)  scr bf16 per-wave [16 rows][64], row-XOR swz, 2KB/wave
#define SCR_OFF 65536

__global__ __launch_bounds__(512, 4) void k_main(
    const float* __restrict__ alpha, const float* __restrict__ w1, const float* __restrict__ b1,
    const float* __restrict__ w2, const float* __restrict__ b2, const float* __restrict__ eps_p,
    const unsigned int* __restrict__ mask, const float* __restrict__ S,
    float* __restrict__ out)
{
    extern __shared__ char smem[];

    const int w    = blockIdx.x;
    const int t    = threadIdx.x;
    const int lane = t & 63;
    const int wid  = t >> 6;
    const int nlo  = lane & 15;
    const int g    = lane >> 4;

    // ---- phase 1: stage AwT (bf16, transposed, swizzled), register-light ----
    {
        const float* src = alpha + (size_t)w * (NV * NF);
#pragma unroll
        for (int i = 0; i < 2; ++i) {
            int task = i * 512 + t;          // 1024 tasks: 64 j-blocks x 16 f-quads
            int jb = task >> 4;
            int fq = task & 15;
            unsigned ua[4][4];               // [c][h] packed bf16 pairs
#pragma unroll
            for (int h = 0; h < 4; ++h) {
                f32x4 r0 = *(const f32x4*)(src + (size_t)(jb * 8 + 2 * h) * NF + fq * 4);
                f32x4 r1 = *(const f32x4*)(src + (size_t)(jb * 8 + 2 * h + 1) * NF + fq * 4);
#pragma unroll
                for (int c = 0; c < 4; ++c)
                    ua[c][h] = (unsigned)f2bf(r0[c]) | ((unsigned)f2bf(r1[c]) << 16);
            }
#pragma unroll
            for (int c = 0; c < 4; ++c) {
                BF8 p;
                p.u[0] = ua[c][0]; p.u[1] = ua[c][1]; p.u[2] = ua[c][2]; p.u[3] = ua[c][3];
                *(bf16x8*)(smem + awt_addr(fq * 4 + c, jb * 16)) = p.v;
            }
        }
    }

    // ---- phase 2: mask words for own wave's 4 m-tiles (16 regs) ----
    const int mbase = wid * 64;
    unsigned qm[4][4];
#pragma unroll
    for (int mi = 0; mi < 4; ++mi) {
        const uint4 q = *(const uint4*)(mask + (size_t)(mbase + mi * 16 + nlo) * 16 + g * 4);
        qm[mi][0] = q.x; qm[mi][1] = q.y; qm[mi][2] = q.z; qm[mi][3] = q.w;
    }

    __syncthreads();

    // ---- phase 3: adjacency GEMM, acc[4][4] = 64 AGPRs ----
    f32x4 acc[4][4];
#pragma unroll
    for (int mi = 0; mi < 4; ++mi)
#pragma unroll
        for (int nt = 0; nt < 4; ++nt)
            acc[mi][nt] = (f32x4){0.f, 0.f, 0.f, 0.f};

#pragma unroll
    for (int kq = 0; kq < 4; ++kq)
#pragma unroll
        for (int kr = 0; kr < 4; ++kr) {
            const int kk = kq * 4 + kr;
            const int srcl = kq * 16 + nlo;     // holder lane of word kk for my row
            BF8 afr[4];                          // A-frags for 4 m-tiles (16 regs)
#pragma unroll
            for (int mi = 0; mi < 4; ++mi) {
                unsigned word = (unsigned)__shfl((int)qm[mi][kr], srcl);
                unsigned byteb = (word >> (g * 8)) & 0xFFu;
#pragma unroll
                for (int h = 0; h < 4; ++h) {
                    unsigned b0 = (byteb >> (2 * h)) & 1u;
                    unsigned b1 = (byteb >> (2 * h + 1)) & 1u;
                    afr[mi].u[h] = (b0 ? 0x3F80u : 0u) | (b1 ? 0x3F800000u : 0u);
                }
            }
#pragma unroll
            for (int nt = 0; nt < 4; ++nt) {
                bf16x8 bfr = *(const bf16x8*)(smem + awt_addr(nt * 16 + nlo, kk * 64 + g * 16));
#pragma unroll
                for (int mi = 0; mi < 4; ++mi)
                    acc[mi][nt] = __builtin_amdgcn_mfma_f32_16x16x32_bf16(afr[mi].v, bfr, acc[mi][nt], 0, 0, 0);
            }
        }

    __syncthreads();   // all AwT reads complete

    // ---- phase 4: stage w1T/w2T into first 16KB (AwT region now dead) ----
    if (t < 256) {
        int m  = t >> 7;                  // 0 -> w1, 1 -> w2
        int sub = t & 127;                // 128 tasks per matrix
        int jb = sub >> 4;                // k-block of 8
        int fq = sub & 15;                // n quad
        const float* wsrc = m ? w2 : w1;
        unsigned ua[4][4];
#pragma unroll
        for (int h = 0; h < 4; ++h) {
            f32x4 r0 = *(const f32x4*)(wsrc + (size_t)(jb * 8 + 2 * h) * NF + fq * 4);
            f32x4 r1 = *(const f32x4*)(wsrc + (size_t)(jb * 8 + 2 * h + 1) * NF + fq * 4);
#pragma unroll
            for (int c = 0; c < 4; ++c)
                ua[c][h] = (unsigned)f2bf(r0[c]) | ((unsigned)f2bf(r1[c]) << 16);
        }
#pragma unroll
        for (int c = 0; c < 4; ++c) {
            BF8 p;
            p.u[0] = ua[c][0]; p.u[1] = ua[c][1]; p.u[2] = ua[c][2]; p.u[3] = ua[c][3];
            *(bf16x8*)(smem + wt_addr(m, fq * 4 + c, jb * 16)) = p.v;
        }
    }
    float b1v[4], b2v[4];
#pragma unroll
    for (int nt = 0; nt < 4; ++nt) {
        b1v[nt] = b1[nt * 16 + nlo];
        b2v[nt] = b2[nt * 16 + nlo];
    }
    const float ceps = 1.0f + eps_p[0];

    __syncthreads();

    // ---- phase 5: epilogue per m-tile (weights from LDS, not registers) ----
    char* myscr = smem + SCR_OFF + wid * 2048;   // [16][64] bf16, row 128B, XOR swz
#pragma unroll
    for (int mi = 0; mi < 4; ++mi) {
        int v0 = mbase + mi * 16;
#pragma unroll
        for (int nt = 0; nt < 4; ++nt) {
            int f = nt * 16 + nlo;
#pragma unroll
            for (int r = 0; r < 4; ++r) {
                int v = v0 + g * 4 + r;
                float pre = acc[mi][nt][r] + S[v * NF + f]
                          + ceps * alpha[((size_t)v * NV + w) * NF + f];
                int row = g * 4 + r;
                *(unsigned short*)(myscr + row * 128 + ((2 * f) ^ ((row & 7) << 4))) = f2bf(pre);
            }
        }

        // layer 1  (A: row nlo, k-bytes g*16 + ks*64, row-XOR swz; B from LDS wT)
        bf16x8 a0 = *(const bf16x8*)(myscr + nlo * 128 + ((g * 16) ^ ((nlo & 7) << 4)));
        bf16x8 a1 = *(const bf16x8*)(myscr + nlo * 128 + ((g * 16 + 64) ^ ((nlo & 7) << 4)));
        f32x4 accm[4];
#pragma unroll
        for (int nt = 0; nt < 4; ++nt) {
            bf16x8 wf0 = *(const bf16x8*)(smem + wt_addr(0, nt * 16 + nlo, g * 16));
            bf16x8 wf1 = *(const bf16x8*)(smem + wt_addr(0, nt * 16 + nlo, 64 + g * 16));
            f32x4 z = {0.f, 0.f, 0.f, 0.f};
            z = __builtin_amdgcn_mfma_f32_16x16x32_bf16(a0, wf0, z, 0, 0, 0);
            z = __builtin_amdgcn_mfma_f32_16x16x32_bf16(a1, wf1, z, 0, 0, 0);
            accm[nt] = z;
        }

        // relu + b1 -> scr (C/D: row=(l>>4)*4+r, col=nt*16+(l&15))
#pragma unroll
        for (int nt = 0; nt < 4; ++nt)
#pragma unroll
            for (int r = 0; r < 4; ++r) {
                float hv = accm[nt][r] + b1v[nt];
                hv = hv > 0.f ? hv : 0.f;
                int row = g * 4 + r;
                *(unsigned short*)(myscr + row * 128 + ((2 * (nt * 16 + nlo)) ^ ((row & 7) << 4))) = f2bf(hv);
            }

        // layer 2
        bf16x8 h0 = *(const bf16x8*)(myscr + nlo * 128 + ((g * 16) ^ ((nlo & 7) << 4)));
        bf16x8 h1 = *(const bf16x8*)(myscr + nlo * 128 + ((g * 16 + 64) ^ ((nlo & 7) << 4)));
#pragma unroll
        for (int nt = 0; nt < 4; ++nt) {
            bf16x8 wf0 = *(const bf16x8*)(smem + wt_addr(1, nt * 16 + nlo, g * 16));
            bf16x8 wf1 = *(const bf16x8*)(smem + wt_addr(1, nt * 16 + nlo, 64 + g * 16));
            f32x4 z = {0.f, 0.f, 0.f, 0.f};
            z = __builtin_amdgcn_mfma_f32_16x16x32_bf16(h0, wf0, z, 0, 0, 0);
            z = __builtin_amdgcn_mfma_f32_16x16x32_bf16(h1, wf1, z, 0, 0, 0);
#pragma unroll
            for (int r = 0; r < 4; ++r) {
                int vv = v0 + g * 4 + r;
                out[((size_t)vv * NV + w) * NF + nt * 16 + nlo] = z[r] + b2v[nt];
            }
        }
    }
}

extern "C" void kernel_launch(void* const* d_in, const int* in_sizes, int n_in,
                              void* d_out, int out_size, void* d_ws, size_t ws_size,
                              hipStream_t stream) {
    const float* alpha = (const float*)d_in[0];
    const int*   ei    = (const int*)d_in[1];
    const float* w1    = (const float*)d_in[2];
    const float* b1    = (const float*)d_in[3];
    const float* w2    = (const float*)d_in[4];
    const float* b2    = (const float*)d_in[5];
    const float* eps   = (const float*)d_in[6];
    float* out = (float*)d_out;
    int E = in_sizes[1] / 2;

    // ws layout (u32/f32 units): mask[8192] | S[512*64]
    unsigned int* mask = (unsigned int*)d_ws;
    float* S = (float*)d_ws + 8192;

    k_zero <<<32, 256, 0, stream>>>(mask);
    k_edges<<<(E + 255) / 256, 256, 0, stream>>>(ei, E, mask);
    k_S    <<<NV, 64, 0, stream>>>(mask, alpha, S);

    const int smem_bytes = 81920;   // 64K AwT(+wT reuse) + 16K scr -> 2 blocks/CU
    hipFuncSetAttribute(reinterpret_cast<const void*>(k_main),
                        hipFuncAttributeMaxDynamicSharedMemorySize, smem_bytes);
    k_main <<<NV, 512, smem_bytes, stream>>>(alpha, w1, b1, w2, b2, eps, mask, S, out);
}